// Round 4
// baseline (221.013 us; speedup 1.0000x reference)
//
#include <hip/hip_runtime.h>

typedef _Float16 f16;
typedef _Float16 f16x4 __attribute__((ext_vector_type(4)));
typedef _Float16 f16x8 __attribute__((ext_vector_type(8)));
typedef float    f32x4 __attribute__((ext_vector_type(4)));

#define NB   8
#define TE   2048
#define TD   2048
#define DIM  256
#define NSPLIT 3
#define LOG2E 1.44269504088896340736f

#define AS1(p) ((const __attribute__((address_space(1))) void*)(p))
#define AS3(p) ((__attribute__((address_space(3))) void*)(p))

// ---------------- prep: enc fp32 -> enc_h f16 (same layout) + enc_t f16 (transposed) ----------------
__global__ __launch_bounds__(256) void prep_kernel(const float* __restrict__ enc,
                                                   f16* __restrict__ ench,
                                                   f16* __restrict__ enct) {
    __shared__ f16 tile[64][72];
    int b  = blockIdx.z;
    int e0 = blockIdx.x * 64;
    int d0 = blockIdx.y * 64;
    int tid = threadIdx.x;
    {
        int e  = tid >> 2;
        int dg = (tid & 3) * 16;
        const float* p = enc + ((size_t)b * TE + e0 + e) * DIM + d0 + dg;
        float4 v0 = *(const float4*)(p);
        float4 v1 = *(const float4*)(p + 4);
        float4 v2 = *(const float4*)(p + 8);
        float4 v3 = *(const float4*)(p + 12);
        f16x8 o0, o1;
        o0[0]=(f16)v0.x; o0[1]=(f16)v0.y; o0[2]=(f16)v0.z; o0[3]=(f16)v0.w;
        o0[4]=(f16)v1.x; o0[5]=(f16)v1.y; o0[6]=(f16)v1.z; o0[7]=(f16)v1.w;
        o1[0]=(f16)v2.x; o1[1]=(f16)v2.y; o1[2]=(f16)v2.z; o1[3]=(f16)v2.w;
        o1[4]=(f16)v3.x; o1[5]=(f16)v3.y; o1[6]=(f16)v3.z; o1[7]=(f16)v3.w;
        *(f16x8*)&tile[e][dg]     = o0;
        *(f16x8*)&tile[e][dg + 8] = o1;
        f16* hp = ench + ((size_t)b * TE + e0 + e) * DIM + d0 + dg;
        *(f16x8*)(hp)     = o0;
        *(f16x8*)(hp + 8) = o1;
    }
    __syncthreads();
    {
        int d  = tid >> 2;
        int eg = (tid & 3) * 16;
        f16x8 o0, o1;
        #pragma unroll
        for (int ii = 0; ii < 8; ii++) o0[ii] = tile[eg + ii][d];
        #pragma unroll
        for (int ii = 0; ii < 8; ii++) o1[ii] = tile[eg + 8 + ii][d];
        f16* qp = enct + ((size_t)b * DIM + d0 + d) * TE + e0 + eg;
        *(f16x8*)(qp)     = o0;
        *(f16x8*)(qp + 8) = o1;
    }
}

// ---------------- fused attention (flash over e, e-split, wave-specialized) ----------------
// block 256 = 4 waves: wave = (th<<1)|dh. th: t-slice of 32, dh: d-half of 128.
// heavy wave (dh == xb&1): QK + softmax + publish P,alpha; light wave: PV only.
// 3 blocks/CU (LDS 54,272 x 3 = 162,816 <= 163,840; launch_bounds(256,3)).
#define LDS_NAT0 0
#define LDS_NAT1 16384
#define LDS_TR   32768
#define LDS_P    49152      // + th*2560 ; rows: 64B P data + alpha@72 + pad ; total 54,272

__global__ __launch_bounds__(256, 3) void attn_kernel(
        const float* __restrict__ dec32,
        const f16*  __restrict__ enc_h,
        const f16*  __restrict__ enc_t,
        float* __restrict__ out,
        f16*   __restrict__ ctxp,
        float* __restrict__ m_arr,
        float* __restrict__ l_arr,
        int nsplit) {
    __shared__ char lds[54272];
    const int tid  = threadIdx.x;
    const int lane = tid & 63;
    const int wave = tid >> 6;
    const int th   = wave >> 1;   // t-slice of 32
    const int dh   = wave & 1;    // d-half of 128
    const int tcol = lane & 15;
    const int q    = lane >> 4;

    // XCD-aware swizzle: 32 t-blocks sharing (b, e-range) -> one XCD (3 groups/XCD)
    int xb, b, z, iters, e_base;
    if (nsplit == NSPLIT) {
        int fid = blockIdx.x + 32 * (blockIdx.y + 8 * blockIdx.z);
        int c = fid & 7, j = fid >> 3;
        xb = j & 31;
        int p = c * 3 + (j >> 5);     // 0..23
        b = p & 7; z = p >> 3;        // z 0..2
        iters  = (z == 0) ? 22 : 21;
        e_base = (z == 0) ? 0 : (704 + (z - 1) * 672);
    } else { xb = blockIdx.x; b = blockIdx.y; z = 0; iters = 64; e_base = 0; }
    const int  t0    = xb * 64;
    const bool heavy = (dh == (xb & 1));   // parity-alternate so heavy waves spread SIMDs

    const f16* enc_b  = enc_h + (size_t)b * TE * DIM;
    const f16* enct_b = enc_t + (size_t)b * DIM * TE;

    // staging bases (global_load_lds: wave-uniform LDS base + lane*16); i-step is const
    const int e00 = tid >> 5, cs0 = tid & 31;
    const int nat_g0 = e00 * DIM + (cs0 ^ (e00 & 7)) * 8;            // + e0*DIM + i*2048
    const int d00 = tid >> 2, c00 = tid & 3;
    const int tr_g0  = d00 * TE + (c00 ^ ((d00 >> 1) & 3)) * 8;      // + e0 + i*64*TE
    const int l0     = wave * 1024;                                   // + i*4096 (+lane*16 HW)

    // preload NAT(0); Q-build overlaps its latency
    #pragma unroll
    for (int i = 0; i < 4; i++)
        __builtin_amdgcn_global_load_lds(AS1(enc_b + (size_t)e_base * DIM + nat_g0 + i * 2048),
                                         AS3(lds + LDS_NAT0 + l0 + i * 4096), 16, 0, 0);

    // monolithic fallback: decoder passthrough here
    if (nsplit == 1) {
        const float* dp = dec32 + ((size_t)b * TD + t0) * DIM;
        float*       op = out   + ((size_t)b * TD + t0) * 512;
        #pragma unroll
        for (int i = 0; i < 16; i++) {
            int idx = i * 256 + tid;
            int t = idx >> 6, c = idx & 63;
            float4 v = *(const float4*)(dp + t * DIM + c * 4);
            *(float4*)(op + t * 512 + c * 4) = v;
        }
    }

    // Q fragments (heavy only): B-operand B[k=q*8+j][n=tcol], resident in regs
    f16x8 qf[2][8];
    if (heavy) {
        const float* qp = dec32 + ((size_t)b * TD + t0 + th * 32) * DIM;
        #pragma unroll
        for (int tn = 0; tn < 2; tn++)
            #pragma unroll
            for (int ks = 0; ks < 8; ks++) {
                const float* p = qp + (size_t)(tn * 16 + tcol) * DIM + ks * 32 + q * 8;
                float4 u = *(const float4*)(p);
                float4 v = *(const float4*)(p + 4);
                f16x8 o;
                o[0]=(f16)u.x; o[1]=(f16)u.y; o[2]=(f16)u.z; o[3]=(f16)u.w;
                o[4]=(f16)v.x; o[5]=(f16)v.y; o[6]=(f16)v.z; o[7]=(f16)v.w;
                qf[tn][ks] = o;
            }
    }

    f16x8 ones;
    #pragma unroll
    for (int j = 0; j < 8; j++) ones[j] = (f16)1.0f;

    const f32x4 zero4 = {0.f, 0.f, 0.f, 0.f};
    float m_[2] = {-INFINITY, -INFINITY};
    f32x4 lsum[2] = {zero4, zero4};
    f32x4 ctx[8][2];
    #pragma unroll
    for (int dm = 0; dm < 8; dm++)
        #pragma unroll
        for (int tn = 0; tn < 2; tn++) ctx[dm][tn] = zero4;

    char* pb = lds + LDS_P + th * 2560;   // P[32 t][80 B row: 64B data + alpha@72]
    const int e7 = tcol & 7;

    __syncthreads();   // NAT(0) visible

    for (int it = 0; it < iters; it++) {
        const int natc = (it & 1) ? LDS_NAT1 : LDS_NAT0;
        const int e0   = e_base + it * 32;

        // issue TR(it) at top (consumed after mid barrier)
        #pragma unroll
        for (int i = 0; i < 4; i++)
            __builtin_amdgcn_global_load_lds(AS1(enct_b + e0 + tr_g0 + i * 64 * TE),
                                             AS3(lds + LDS_TR + l0 + i * 4096), 16, 0, 0);

        if (heavy) {
            // ---- QK: St[e 32][t 32-slice] ----
            f32x4 st[2][2];
            #pragma unroll
            for (int mt = 0; mt < 2; mt++)
                #pragma unroll
                for (int tn = 0; tn < 2; tn++) st[mt][tn] = zero4;
            #pragma unroll
            for (int ks = 0; ks < 8; ks++) {
                #pragma unroll
                for (int mt = 0; mt < 2; mt++) {
                    int e = mt * 16 + tcol;
                    f16x8 af = *(const f16x8*)(lds + natc + e * 512 + (((ks << 2) | q) ^ e7) * 16);
                    #pragma unroll
                    for (int tn = 0; tn < 2; tn++)
                        st[mt][tn] = __builtin_amdgcn_mfma_f32_16x16x32_f16(af, qf[tn][ks], st[mt][tn], 0, 0, 0);
                }
            }
            // ---- online softmax + publish P, alpha ----
            #pragma unroll
            for (int tn = 0; tn < 2; tn++) {
                float mx = fmaxf(fmaxf(fmaxf(st[0][tn][0], st[0][tn][1]), fmaxf(st[0][tn][2], st[0][tn][3])),
                                 fmaxf(fmaxf(st[1][tn][0], st[1][tn][1]), fmaxf(st[1][tn][2], st[1][tn][3])));
                mx = fmaxf(mx, __shfl_xor(mx, 16, 64));
                mx = fmaxf(mx, __shfl_xor(mx, 32, 64));
                float mn = fmaxf(m_[tn], mx);
                bool bumped = mn > m_[tn];
                float al = __builtin_amdgcn_exp2f((m_[tn] - mn) * LOG2E);
                m_[tn] = mn;
                char* prow = pb + (tn * 16 + tcol) * 80;
                #pragma unroll
                for (int mt = 0; mt < 2; mt++) {
                    f16x4 pv;
                    #pragma unroll
                    for (int r = 0; r < 4; r++)
                        pv[r] = (f16)__builtin_amdgcn_exp2f((st[mt][tn][r] - mn) * LOG2E);
                    *(f16x4*)(prow + mt * 32 + q * 8) = pv;   // e = mt*16+q*4..+4
                }
                if (q == 0) *(float*)(prow + 72) = al;        // alpha in row pad
                if (__any(bumped)) {
                    lsum[tn][0] *= al; lsum[tn][1] *= al; lsum[tn][2] *= al; lsum[tn][3] *= al;
                    #pragma unroll
                    for (int dm = 0; dm < 8; dm++) {
                        ctx[dm][tn][0] *= al; ctx[dm][tn][1] *= al;
                        ctx[dm][tn][2] *= al; ctx[dm][tn][3] *= al;
                    }
                }
            }
        }

        __syncthreads();   // TR(it) + P + alpha visible

        // prefetch NAT(it+1) (drained at end barrier, covered by PV)
        if (it + 1 < iters) {
            const int natn = (it & 1) ? LDS_NAT0 : LDS_NAT1;
            #pragma unroll
            for (int i = 0; i < 4; i++)
                __builtin_amdgcn_global_load_lds(AS1(enc_b + (size_t)(e0 + 32) * DIM + nat_g0 + i * 2048),
                                                 AS3(lds + natn + l0 + i * 4096), 16, 0, 0);
        }

        // light wave: adopt alpha, rescale its accumulators
        if (!heavy) {
            #pragma unroll
            for (int tn = 0; tn < 2; tn++) {
                float al = *(const float*)(pb + (tn * 16 + tcol) * 80 + 72);
                if (__any(al < 1.0f)) {
                    lsum[tn][0] *= al; lsum[tn][1] *= al; lsum[tn][2] *= al; lsum[tn][3] *= al;
                    #pragma unroll
                    for (int dm = 0; dm < 8; dm++) {
                        ctx[dm][tn][0] *= al; ctx[dm][tn][1] *= al;
                        ctx[dm][tn][2] *= al; ctx[dm][tn][3] *= al;
                    }
                }
            }
        }

        // ---- PV: ctxT[d][t] += enc_t * P ; l via ones row ----
        f16x8 pf[2];
        #pragma unroll
        for (int tn = 0; tn < 2; tn++)
            pf[tn] = *(const f16x8*)(pb + (tn * 16 + tcol) * 80 + q * 16);
        #pragma unroll
        for (int tn = 0; tn < 2; tn++)
            lsum[tn] = __builtin_amdgcn_mfma_f32_16x16x32_f16(ones, pf[tn], lsum[tn], 0, 0, 0);
        #pragma unroll
        for (int dm = 0; dm < 8; dm++) {
            int drow = dh * 128 + dm * 16 + tcol;
            f16x8 af = *(const f16x8*)(lds + LDS_TR + drow * 64 + (q ^ ((tcol >> 1) & 3)) * 16);
            #pragma unroll
            for (int tn = 0; tn < 2; tn++)
                ctx[dm][tn] = __builtin_amdgcn_mfma_f32_16x16x32_f16(af, pf[tn], ctx[dm][tn], 0, 0, 0);
        }

        __syncthreads();   // TR/P reads done + NAT(it+1) drained before next iter
    }

    // ---- epilogue ----
    if (nsplit > 1) {
        size_t rowbase = (size_t)(z * NB + b) * TD + t0 + th * 32;
        #pragma unroll
        for (int tn = 0; tn < 2; tn++) {
            float inv = 1.0f / lsum[tn][0];
            size_t rb = (rowbase + tn * 16 + tcol) * DIM + dh * 128;
            #pragma unroll
            for (int dm = 0; dm < 8; dm++) {
                f16x4 cv;
                #pragma unroll
                for (int r = 0; r < 4; r++) cv[r] = (f16)(ctx[dm][tn][r] * inv);
                *(f16x4*)(ctxp + rb + dm * 16 + q * 4) = cv;
            }
        }
        if (heavy && lane < 16) {
            int mi = (z * NB + b) * TD + t0 + th * 32 + lane;
            #pragma unroll
            for (int tn = 0; tn < 2; tn++) {
                m_arr[mi + tn * 16] = m_[tn];
                l_arr[mi + tn * 16] = lsum[tn][0];
            }
        }
    } else {
        float* ob = out + ((size_t)b * TD + t0 + th * 32) * 512 + 256 + dh * 128;
        #pragma unroll
        for (int tn = 0; tn < 2; tn++) {
            float inv = 1.0f / lsum[tn][0];
            #pragma unroll
            for (int dm = 0; dm < 8; dm++)
                #pragma unroll
                for (int r = 0; r < 4; r++)
                    ob[(size_t)(tn * 16 + tcol) * 512 + dm * 16 + q * 4 + r] = ctx[dm][tn][r] * inv;
        }
    }
}

// ---------------- combine: merge NSPLIT normalized partials + decoder passthrough ----------------
__global__ __launch_bounds__(256) void combine_kernel(const float* __restrict__ dec32,
        const f16* __restrict__ ctxp, const float* __restrict__ m_arr,
        const float* __restrict__ l_arr, float* __restrict__ out) {
    int idx  = blockIdx.x * 256 + threadIdx.x;
    int trow = idx >> 5;              // b*TD + t
    int dg   = (idx & 31) * 8;
    float m0[NSPLIT], l0[NSPLIT], M = -INFINITY;
    #pragma unroll
    for (int s = 0; s < NSPLIT; s++) {
        m0[s] = m_arr[s * (NB * TD) + trow];
        l0[s] = l_arr[s * (NB * TD) + trow];
        M = fmaxf(M, m0[s]);
    }
    float L = 0.f, w[NSPLIT];
    #pragma unroll
    for (int s = 0; s < NSPLIT; s++) {
        w[s] = __builtin_amdgcn_exp2f((m0[s] - M) * LOG2E) * l0[s];
        L += w[s];
    }
    float invL = 1.0f / L;
    float acc[8] = {0.f,0.f,0.f,0.f,0.f,0.f,0.f,0.f};
    #pragma unroll
    for (int s = 0; s < NSPLIT; s++) {
        f16x8 v = *(const f16x8*)(ctxp + ((size_t)s * (NB * TD) + trow) * DIM + dg);
        float ws = w[s] * invL;
        #pragma unroll
        for (int j = 0; j < 8; j++) acc[j] += ws * (float)v[j];
    }
    float4 d0 = *(const float4*)(dec32 + (size_t)trow * DIM + dg);
    float4 d1 = *(const float4*)(dec32 + (size_t)trow * DIM + dg + 4);
    float* ob = out + (size_t)trow * 512;
    *(float4*)(ob + dg)     = d0;
    *(float4*)(ob + dg + 4) = d1;
    float4 c0, c1;
    c0.x=acc[0]; c0.y=acc[1]; c0.z=acc[2]; c0.w=acc[3];
    c1.x=acc[4]; c1.y=acc[5]; c1.z=acc[6]; c1.w=acc[7];
    *(float4*)(ob + 256 + dg)     = c0;
    *(float4*)(ob + 256 + dg + 4) = c1;
}

extern "C" void kernel_launch(void* const* d_in, const int* in_sizes, int n_in,
                              void* d_out, int out_size, void* d_ws, size_t ws_size,
                              hipStream_t stream) {
    (void)in_sizes; (void)n_in;
    const float* enc = (const float*)d_in[0];
    const float* dec = (const float*)d_in[1];
    float* out = (float*)d_out;

    const size_t HB    = (size_t)NB * TE * DIM * 2;            // 8,388,608
    const size_t CTXPB = (size_t)NSPLIT * NB * TD * DIM * 2;   // 25,165,824
    const size_t MLB   = (size_t)NSPLIT * NB * TD * 4;         // 196,608
    const size_t NEED3 = 2 * HB + CTXPB + 2 * MLB;             // ~42.3 MB
    const size_t NEED1 = 2 * HB;

    if (ws_size < NEED1) {
        hipMemsetAsync(d_out, 0, (size_t)out_size * sizeof(float), stream);
        return;
    }
    int nsplit = (ws_size >= NEED3) ? NSPLIT : 1;

    f16*   enc_h = (f16*)d_ws;
    f16*   enc_t = (f16*)((char*)d_ws + HB);
    f16*   ctxp  = (f16*)((char*)d_ws + 2 * HB);
    float* m_arr = (float*)((char*)d_ws + 2 * HB + CTXPB);
    float* l_arr = (float*)((char*)d_ws + 2 * HB + CTXPB + MLB);

    prep_kernel<<<dim3(32, 4, 8), 256, 0, stream>>>(enc, enc_h, enc_t);
    attn_kernel<<<dim3(32, 8, nsplit), 256, 0, stream>>>(dec, enc_h, enc_t, out,
                                                         ctxp, m_arr, l_arr, nsplit);
    if (nsplit == NSPLIT)
        combine_kernel<<<2048, 256, 0, stream>>>(dec, ctxp, m_arr, l_arr, out);
}

// Round 5
// 175.205 us; speedup vs baseline: 1.2615x; 1.2615x over previous
//
#include <hip/hip_runtime.h>

typedef _Float16 f16;
typedef _Float16 f16x4 __attribute__((ext_vector_type(4)));
typedef _Float16 f16x8 __attribute__((ext_vector_type(8)));
typedef float    f32x4 __attribute__((ext_vector_type(4)));

#define NB   8
#define TE   2048
#define TD   2048
#define DIM  256
#define NSPLIT 3
#define LOG2E 1.44269504088896340736f

#define AS1(p) ((const __attribute__((address_space(1))) void*)(p))
#define AS3(p) ((__attribute__((address_space(3))) void*)(p))

// ---------------- prep: enc fp32 -> enc_h f16 (same layout) + enc_t f16 (transposed) ----------------
__global__ __launch_bounds__(256) void prep_kernel(const float* __restrict__ enc,
                                                   f16* __restrict__ ench,
                                                   f16* __restrict__ enct) {
    __shared__ f16 tile[64][72];
    int b  = blockIdx.z;
    int e0 = blockIdx.x * 64;
    int d0 = blockIdx.y * 64;
    int tid = threadIdx.x;
    {
        int e  = tid >> 2;
        int dg = (tid & 3) * 16;
        const float* p = enc + ((size_t)b * TE + e0 + e) * DIM + d0 + dg;
        float4 v0 = *(const float4*)(p);
        float4 v1 = *(const float4*)(p + 4);
        float4 v2 = *(const float4*)(p + 8);
        float4 v3 = *(const float4*)(p + 12);
        f16x8 o0, o1;
        o0[0]=(f16)v0.x; o0[1]=(f16)v0.y; o0[2]=(f16)v0.z; o0[3]=(f16)v0.w;
        o0[4]=(f16)v1.x; o0[5]=(f16)v1.y; o0[6]=(f16)v1.z; o0[7]=(f16)v1.w;
        o1[0]=(f16)v2.x; o1[1]=(f16)v2.y; o1[2]=(f16)v2.z; o1[3]=(f16)v2.w;
        o1[4]=(f16)v3.x; o1[5]=(f16)v3.y; o1[6]=(f16)v3.z; o1[7]=(f16)v3.w;
        *(f16x8*)&tile[e][dg]     = o0;
        *(f16x8*)&tile[e][dg + 8] = o1;
        f16* hp = ench + ((size_t)b * TE + e0 + e) * DIM + d0 + dg;
        *(f16x8*)(hp)     = o0;
        *(f16x8*)(hp + 8) = o1;
    }
    __syncthreads();
    {
        int d  = tid >> 2;
        int eg = (tid & 3) * 16;
        f16x8 o0, o1;
        #pragma unroll
        for (int ii = 0; ii < 8; ii++) o0[ii] = tile[eg + ii][d];
        #pragma unroll
        for (int ii = 0; ii < 8; ii++) o1[ii] = tile[eg + 8 + ii][d];
        f16* qp = enct + ((size_t)b * DIM + d0 + d) * TE + e0 + eg;
        *(f16x8*)(qp)     = o0;
        *(f16x8*)(qp + 8) = o1;
    }
}

// ---------------- fused attention (flash over e, e-split, wave-specialized) ----------------
// block 256 = 4 waves: wave = (th<<1)|dh. th: t-slice of 32, dh: d-half of 128.
// heavy wave (dh == xb&1): QK + softmax + publish P,alpha; light wave: PV only.
// SINGLE-buffered NAT: its only readers (heavy QK) finish before the mid barrier,
// so NAT(it+1) global_load_lds is issued right after the mid barrier into the same
// buffer (PV phase covers latency; end barrier drains). LDS 37,888 B -> 3 blocks/CU
// with big headroom. NSPLIT=3: 768 blocks = exactly 3/CU, single round, no tail.
#define LDS_NAT 0
#define LDS_TR  16384
#define LDS_P   32768      // + th*2560 ; rows: 64B P data + alpha@72 + pad ; total 37,888

__global__ __launch_bounds__(256, 3) void attn_kernel(
        const float* __restrict__ dec32,
        const f16*  __restrict__ enc_h,
        const f16*  __restrict__ enc_t,
        float* __restrict__ out,
        f16*   __restrict__ ctxp,
        float* __restrict__ m_arr,
        float* __restrict__ l_arr,
        int nsplit) {
    __shared__ char lds[37888];
    const int tid  = threadIdx.x;
    const int lane = tid & 63;
    const int wave = tid >> 6;
    const int th   = wave >> 1;   // t-slice of 32
    const int dh   = wave & 1;    // d-half of 128
    const int tcol = lane & 15;
    const int q    = lane >> 4;

    // XCD-aware swizzle: 32 t-blocks sharing (b, e-range) -> one XCD (3 groups/XCD)
    int xb, b, z, iters, e_base;
    if (nsplit == NSPLIT) {
        int fid = blockIdx.x + 32 * (blockIdx.y + 8 * blockIdx.z);
        int c = fid & 7, j = fid >> 3;
        xb = j & 31;
        int p = c * 3 + (j >> 5);     // 0..23
        b = p & 7; z = p >> 3;        // z 0..2
        iters  = (z == 0) ? 22 : 21;
        e_base = (z == 0) ? 0 : (704 + (z - 1) * 672);
    } else { xb = blockIdx.x; b = blockIdx.y; z = 0; iters = 64; e_base = 0; }
    const int  t0    = xb * 64;
    const bool heavy = (dh == (xb & 1));   // parity-alternate so heavy waves spread SIMDs

    const f16* enc_b  = enc_h + (size_t)b * TE * DIM;
    const f16* enct_b = enc_t + (size_t)b * DIM * TE;

    // staging bases (global_load_lds: wave-uniform LDS base + lane*16); i-step is const
    const int e00 = tid >> 5, cs0 = tid & 31;
    const int nat_g0 = e00 * DIM + (cs0 ^ (e00 & 7)) * 8;            // + e0*DIM + i*2048
    const int d00 = tid >> 2, c00 = tid & 3;
    const int tr_g0  = d00 * TE + (c00 ^ ((d00 >> 1) & 3)) * 8;      // + e0 + i*64*TE
    const int l0     = wave * 1024;                                   // + i*4096 (+lane*16 HW)

    // preload NAT(0); Q-build overlaps its latency
    #pragma unroll
    for (int i = 0; i < 4; i++)
        __builtin_amdgcn_global_load_lds(AS1(enc_b + (size_t)e_base * DIM + nat_g0 + i * 2048),
                                         AS3(lds + LDS_NAT + l0 + i * 4096), 16, 0, 0);

    // monolithic fallback: decoder passthrough here
    if (nsplit == 1) {
        const float* dp = dec32 + ((size_t)b * TD + t0) * DIM;
        float*       op = out   + ((size_t)b * TD + t0) * 512;
        #pragma unroll
        for (int i = 0; i < 16; i++) {
            int idx = i * 256 + tid;
            int t = idx >> 6, c = idx & 63;
            float4 v = *(const float4*)(dp + t * DIM + c * 4);
            *(float4*)(op + t * 512 + c * 4) = v;
        }
    }

    // Q fragments (heavy only): B-operand B[k=q*8+j][n=tcol], resident in regs
    f16x8 qf[2][8];
    if (heavy) {
        const float* qp = dec32 + ((size_t)b * TD + t0 + th * 32) * DIM;
        #pragma unroll
        for (int tn = 0; tn < 2; tn++)
            #pragma unroll
            for (int ks = 0; ks < 8; ks++) {
                const float* p = qp + (size_t)(tn * 16 + tcol) * DIM + ks * 32 + q * 8;
                float4 u = *(const float4*)(p);
                float4 v = *(const float4*)(p + 4);
                f16x8 o;
                o[0]=(f16)u.x; o[1]=(f16)u.y; o[2]=(f16)u.z; o[3]=(f16)u.w;
                o[4]=(f16)v.x; o[5]=(f16)v.y; o[6]=(f16)v.z; o[7]=(f16)v.w;
                qf[tn][ks] = o;
            }
    }

    f16x8 ones;
    #pragma unroll
    for (int j = 0; j < 8; j++) ones[j] = (f16)1.0f;

    const f32x4 zero4 = {0.f, 0.f, 0.f, 0.f};
    float m_[2] = {-INFINITY, -INFINITY};
    f32x4 lsum[2] = {zero4, zero4};
    f32x4 ctx[8][2];
    #pragma unroll
    for (int dm = 0; dm < 8; dm++)
        #pragma unroll
        for (int tn = 0; tn < 2; tn++) ctx[dm][tn] = zero4;

    char* pb = lds + LDS_P + th * 2560;   // P[32 t][80 B row: 64B data + alpha@72]
    const int e7 = tcol & 7;

    __syncthreads();   // NAT(0) visible

    for (int it = 0; it < iters; it++) {
        const int e0 = e_base + it * 32;

        // issue TR(it) at top (consumed after mid barrier)
        #pragma unroll
        for (int i = 0; i < 4; i++)
            __builtin_amdgcn_global_load_lds(AS1(enct_b + e0 + tr_g0 + i * 64 * TE),
                                             AS3(lds + LDS_TR + l0 + i * 4096), 16, 0, 0);

        if (heavy) {
            // ---- QK: St[e 32][t 32-slice] ----
            f32x4 st[2][2];
            #pragma unroll
            for (int mt = 0; mt < 2; mt++)
                #pragma unroll
                for (int tn = 0; tn < 2; tn++) st[mt][tn] = zero4;
            #pragma unroll
            for (int ks = 0; ks < 8; ks++) {
                #pragma unroll
                for (int mt = 0; mt < 2; mt++) {
                    int e = mt * 16 + tcol;
                    f16x8 af = *(const f16x8*)(lds + LDS_NAT + e * 512 + (((ks << 2) | q) ^ e7) * 16);
                    #pragma unroll
                    for (int tn = 0; tn < 2; tn++)
                        st[mt][tn] = __builtin_amdgcn_mfma_f32_16x16x32_f16(af, qf[tn][ks], st[mt][tn], 0, 0, 0);
                }
            }
            // ---- online softmax + publish P, alpha ----
            #pragma unroll
            for (int tn = 0; tn < 2; tn++) {
                float mx = fmaxf(fmaxf(fmaxf(st[0][tn][0], st[0][tn][1]), fmaxf(st[0][tn][2], st[0][tn][3])),
                                 fmaxf(fmaxf(st[1][tn][0], st[1][tn][1]), fmaxf(st[1][tn][2], st[1][tn][3])));
                mx = fmaxf(mx, __shfl_xor(mx, 16, 64));
                mx = fmaxf(mx, __shfl_xor(mx, 32, 64));
                float mn = fmaxf(m_[tn], mx);
                bool bumped = mn > m_[tn];
                float al = __builtin_amdgcn_exp2f((m_[tn] - mn) * LOG2E);
                m_[tn] = mn;
                char* prow = pb + (tn * 16 + tcol) * 80;
                #pragma unroll
                for (int mt = 0; mt < 2; mt++) {
                    f16x4 pv;
                    #pragma unroll
                    for (int r = 0; r < 4; r++)
                        pv[r] = (f16)__builtin_amdgcn_exp2f((st[mt][tn][r] - mn) * LOG2E);
                    *(f16x4*)(prow + mt * 32 + q * 8) = pv;   // e = mt*16+q*4..+4
                }
                if (q == 0) *(float*)(prow + 72) = al;        // alpha in row pad
                if (__any(bumped)) {
                    lsum[tn][0] *= al; lsum[tn][1] *= al; lsum[tn][2] *= al; lsum[tn][3] *= al;
                    #pragma unroll
                    for (int dm = 0; dm < 8; dm++) {
                        ctx[dm][tn][0] *= al; ctx[dm][tn][1] *= al;
                        ctx[dm][tn][2] *= al; ctx[dm][tn][3] *= al;
                    }
                }
            }
        }

        __syncthreads();   // TR(it) + P + alpha visible; all NAT(it) QK reads done

        // stage NAT(it+1) into the SAME buffer (safe: all readers passed mid barrier;
        // PV covers the latency; end barrier drains completion)
        if (it + 1 < iters) {
            #pragma unroll
            for (int i = 0; i < 4; i++)
                __builtin_amdgcn_global_load_lds(AS1(enc_b + (size_t)(e0 + 32) * DIM + nat_g0 + i * 2048),
                                                 AS3(lds + LDS_NAT + l0 + i * 4096), 16, 0, 0);
        }

        // light wave: adopt alpha, rescale its accumulators
        if (!heavy) {
            #pragma unroll
            for (int tn = 0; tn < 2; tn++) {
                float al = *(const float*)(pb + (tn * 16 + tcol) * 80 + 72);
                if (__any(al < 1.0f)) {
                    lsum[tn][0] *= al; lsum[tn][1] *= al; lsum[tn][2] *= al; lsum[tn][3] *= al;
                    #pragma unroll
                    for (int dm = 0; dm < 8; dm++) {
                        ctx[dm][tn][0] *= al; ctx[dm][tn][1] *= al;
                        ctx[dm][tn][2] *= al; ctx[dm][tn][3] *= al;
                    }
                }
            }
        }

        // ---- PV: ctxT[d][t] += enc_t * P ; l via ones row ----
        f16x8 pf[2];
        #pragma unroll
        for (int tn = 0; tn < 2; tn++)
            pf[tn] = *(const f16x8*)(pb + (tn * 16 + tcol) * 80 + q * 16);
        #pragma unroll
        for (int tn = 0; tn < 2; tn++)
            lsum[tn] = __builtin_amdgcn_mfma_f32_16x16x32_f16(ones, pf[tn], lsum[tn], 0, 0, 0);
        #pragma unroll
        for (int dm = 0; dm < 8; dm++) {
            int drow = dh * 128 + dm * 16 + tcol;
            f16x8 af = *(const f16x8*)(lds + LDS_TR + drow * 64 + (q ^ ((tcol >> 1) & 3)) * 16);
            #pragma unroll
            for (int tn = 0; tn < 2; tn++)
                ctx[dm][tn] = __builtin_amdgcn_mfma_f32_16x16x32_f16(af, pf[tn], ctx[dm][tn], 0, 0, 0);
        }

        __syncthreads();   // TR/P reads done + NAT(it+1) drained before next iter
    }

    // ---- epilogue ----
    if (nsplit > 1) {
        size_t rowbase = (size_t)(z * NB + b) * TD + t0 + th * 32;
        #pragma unroll
        for (int tn = 0; tn < 2; tn++) {
            float inv = 1.0f / lsum[tn][0];
            size_t rb = (rowbase + tn * 16 + tcol) * DIM + dh * 128;
            #pragma unroll
            for (int dm = 0; dm < 8; dm++) {
                f16x4 cv;
                #pragma unroll
                for (int r = 0; r < 4; r++) cv[r] = (f16)(ctx[dm][tn][r] * inv);
                *(f16x4*)(ctxp + rb + dm * 16 + q * 4) = cv;
            }
        }
        if (heavy && lane < 16) {
            int mi = (z * NB + b) * TD + t0 + th * 32 + lane;
            #pragma unroll
            for (int tn = 0; tn < 2; tn++) {
                m_arr[mi + tn * 16] = m_[tn];
                l_arr[mi + tn * 16] = lsum[tn][0];
            }
        }
    } else {
        float* ob = out + ((size_t)b * TD + t0 + th * 32) * 512 + 256 + dh * 128;
        #pragma unroll
        for (int tn = 0; tn < 2; tn++) {
            float inv = 1.0f / lsum[tn][0];
            #pragma unroll
            for (int dm = 0; dm < 8; dm++)
                #pragma unroll
                for (int r = 0; r < 4; r++)
                    ob[(size_t)(tn * 16 + tcol) * 512 + dm * 16 + q * 4 + r] = ctx[dm][tn][r] * inv;
        }
    }
}

// ---------------- combine: merge NSPLIT normalized partials + decoder passthrough ----------------
__global__ __launch_bounds__(256) void combine_kernel(const float* __restrict__ dec32,
        const f16* __restrict__ ctxp, const float* __restrict__ m_arr,
        const float* __restrict__ l_arr, float* __restrict__ out) {
    int idx  = blockIdx.x * 256 + threadIdx.x;
    int trow = idx >> 5;              // b*TD + t
    int dg   = (idx & 31) * 8;
    float m0[NSPLIT], l0[NSPLIT], M = -INFINITY;
    #pragma unroll
    for (int s = 0; s < NSPLIT; s++) {
        m0[s] = m_arr[s * (NB * TD) + trow];
        l0[s] = l_arr[s * (NB * TD) + trow];
        M = fmaxf(M, m0[s]);
    }
    float L = 0.f, w[NSPLIT];
    #pragma unroll
    for (int s = 0; s < NSPLIT; s++) {
        w[s] = __builtin_amdgcn_exp2f((m0[s] - M) * LOG2E) * l0[s];
        L += w[s];
    }
    float invL = 1.0f / L;
    float acc[8] = {0.f,0.f,0.f,0.f,0.f,0.f,0.f,0.f};
    #pragma unroll
    for (int s = 0; s < NSPLIT; s++) {
        f16x8 v = *(const f16x8*)(ctxp + ((size_t)s * (NB * TD) + trow) * DIM + dg);
        float ws = w[s] * invL;
        #pragma unroll
        for (int j = 0; j < 8; j++) acc[j] += ws * (float)v[j];
    }
    float4 d0 = *(const float4*)(dec32 + (size_t)trow * DIM + dg);
    float4 d1 = *(const float4*)(dec32 + (size_t)trow * DIM + dg + 4);
    float* ob = out + (size_t)trow * 512;
    *(float4*)(ob + dg)     = d0;
    *(float4*)(ob + dg + 4) = d1;
    float4 c0, c1;
    c0.x=acc[0]; c0.y=acc[1]; c0.z=acc[2]; c0.w=acc[3];
    c1.x=acc[4]; c1.y=acc[5]; c1.z=acc[6]; c1.w=acc[7];
    *(float4*)(ob + 256 + dg)     = c0;
    *(float4*)(ob + 256 + dg + 4) = c1;
}

extern "C" void kernel_launch(void* const* d_in, const int* in_sizes, int n_in,
                              void* d_out, int out_size, void* d_ws, size_t ws_size,
                              hipStream_t stream) {
    (void)in_sizes; (void)n_in;
    const float* enc = (const float*)d_in[0];
    const float* dec = (const float*)d_in[1];
    float* out = (float*)d_out;

    const size_t HB    = (size_t)NB * TE * DIM * 2;            // 8,388,608
    const size_t CTXPB = (size_t)NSPLIT * NB * TD * DIM * 2;   // 25,165,824
    const size_t MLB   = (size_t)NSPLIT * NB * TD * 4;         // 196,608
    const size_t NEED3 = 2 * HB + CTXPB + 2 * MLB;             // ~42.3 MB
    const size_t NEED1 = 2 * HB;

    if (ws_size < NEED1) {
        hipMemsetAsync(d_out, 0, (size_t)out_size * sizeof(float), stream);
        return;
    }
    int nsplit = (ws_size >= NEED3) ? NSPLIT : 1;

    f16*   enc_h = (f16*)d_ws;
    f16*   enc_t = (f16*)((char*)d_ws + HB);
    f16*   ctxp  = (f16*)((char*)d_ws + 2 * HB);
    float* m_arr = (float*)((char*)d_ws + 2 * HB + CTXPB);
    float* l_arr = (float*)((char*)d_ws + 2 * HB + CTXPB + MLB);

    prep_kernel<<<dim3(32, 4, 8), 256, 0, stream>>>(enc, enc_h, enc_t);
    attn_kernel<<<dim3(32, 8, nsplit), 256, 0, stream>>>(dec, enc_h, enc_t, out,
                                                         ctxp, m_arr, l_arr, nsplit);
    if (nsplit == NSPLIT)
        combine_kernel<<<2048, 256, 0, stream>>>(dec, ctxp, m_arr, l_arr, out);
}

// Round 6
// 151.977 us; speedup vs baseline: 1.4543x; 1.1528x over previous
//
#include <hip/hip_runtime.h>

typedef _Float16 f16;
typedef _Float16 f16x4 __attribute__((ext_vector_type(4)));
typedef _Float16 f16x8 __attribute__((ext_vector_type(8)));
typedef float    f32x4 __attribute__((ext_vector_type(4)));

#define NB   8
#define TE   2048
#define TD   2048
#define DIM  256
#define NSPLIT 2
#define LOG2E 1.44269504088896340736f

#define AS1(p) ((const __attribute__((address_space(1))) void*)(p))
#define AS3(p) ((__attribute__((address_space(3))) void*)(p))

// ---------------- prep: enc fp32 -> enc_h f16 (same layout) + enc_t f16 (transposed) ----------------
__global__ __launch_bounds__(256) void prep_kernel(const float* __restrict__ enc,
                                                   f16* __restrict__ ench,
                                                   f16* __restrict__ enct) {
    __shared__ f16 tile[64][72];
    int b  = blockIdx.z;
    int e0 = blockIdx.x * 64;
    int d0 = blockIdx.y * 64;
    int tid = threadIdx.x;
    {
        int e  = tid >> 2;
        int dg = (tid & 3) * 16;
        const float* p = enc + ((size_t)b * TE + e0 + e) * DIM + d0 + dg;
        float4 v0 = *(const float4*)(p);
        float4 v1 = *(const float4*)(p + 4);
        float4 v2 = *(const float4*)(p + 8);
        float4 v3 = *(const float4*)(p + 12);
        f16x8 o0, o1;
        o0[0]=(f16)v0.x; o0[1]=(f16)v0.y; o0[2]=(f16)v0.z; o0[3]=(f16)v0.w;
        o0[4]=(f16)v1.x; o0[5]=(f16)v1.y; o0[6]=(f16)v1.z; o0[7]=(f16)v1.w;
        o1[0]=(f16)v2.x; o1[1]=(f16)v2.y; o1[2]=(f16)v2.z; o1[3]=(f16)v2.w;
        o1[4]=(f16)v3.x; o1[5]=(f16)v3.y; o1[6]=(f16)v3.z; o1[7]=(f16)v3.w;
        *(f16x8*)&tile[e][dg]     = o0;
        *(f16x8*)&tile[e][dg + 8] = o1;
        f16* hp = ench + ((size_t)b * TE + e0 + e) * DIM + d0 + dg;
        *(f16x8*)(hp)     = o0;
        *(f16x8*)(hp + 8) = o1;
    }
    __syncthreads();
    {
        int d  = tid >> 2;
        int eg = (tid & 3) * 16;
        f16x8 o0, o1;
        #pragma unroll
        for (int ii = 0; ii < 8; ii++) o0[ii] = tile[eg + ii][d];
        #pragma unroll
        for (int ii = 0; ii < 8; ii++) o1[ii] = tile[eg + 8 + ii][d];
        f16* qp = enct + ((size_t)b * DIM + d0 + d) * TE + e0 + eg;
        *(f16x8*)(qp)     = o0;
        *(f16x8*)(qp + 8) = o1;
    }
}

// ---------------- fused attention: ONE barrier per iter, everything double-buffered ----------------
// block 256 = 4 waves: wave = (th<<1)|dh. th: t-slice of 32, dh: d-half of 128.
// heavy wave (dh == xb&1): QK + softmax + publish P,alpha; light: PV only.
// Schedule per iter:  [QK(it) | softmax | P-write]  MID-BARRIER  [issue TR(it+1),
// NAT(it+2) | light alpha-rescale | PV(it)]  -> loop.
// Race-freedom: NAT(it+2) targets NAT[it&1] whose readers (QK(it)) finished pre-mid;
// TR(it+1)/P(it+1) target alt buffers. Every global_load_lds is issued >= one full
// barrier window before the drain that needs it -> vmcnt(0) at the barrier is ~free.
// LDS 75,776 B -> 2 blocks/CU. NSPLIT=2: 512 blocks = exactly 2/CU, 32 iters, no tail.
#define LDS_NAT0 0
#define LDS_NAT1 16384
#define LDS_TR0  32768
#define LDS_TR1  49152
#define LDS_P    65536     // + (it&1)*5120 + th*2560 ; rows 80B: 64B P + alpha@72 ; tot 75,776

__global__ __launch_bounds__(256, 2) void attn_kernel(
        const float* __restrict__ dec32,
        const f16*  __restrict__ enc_h,
        const f16*  __restrict__ enc_t,
        float* __restrict__ out,
        f16*   __restrict__ ctxp,
        float* __restrict__ m_arr,
        float* __restrict__ l_arr,
        int nsplit) {
    __shared__ char lds[75776];
    const int tid  = threadIdx.x;
    const int lane = tid & 63;
    const int wave = tid >> 6;
    const int th   = wave >> 1;   // t-slice of 32
    const int dh   = wave & 1;    // d-half of 128
    const int tcol = lane & 15;
    const int q    = lane >> 4;

    // XCD-aware swizzle: 32 t-blocks sharing (b,z) -> one XCD; 2 groups/XCD = 64 blk/XCD
    int xb, b, z, iters, e_base;
    if (nsplit == NSPLIT) {
        int fid = blockIdx.x + 32 * (blockIdx.y + 8 * blockIdx.z);
        int c = fid & 7, j = fid >> 3;
        xb = j & 31;
        int g = c * 2 + (j >> 5);     // 0..15
        b = g & 7; z = g >> 3;        // z 0..1
        iters  = 32;
        e_base = z * 1024;
    } else { xb = blockIdx.x; b = blockIdx.y; z = 0; iters = 64; e_base = 0; }
    const int  t0    = xb * 64;
    const bool heavy = (dh == (xb & 1));

    const f16* enc_b  = enc_h + (size_t)b * TE * DIM;
    const f16* enct_b = enc_t + (size_t)b * DIM * TE;

    // staging bases (global_load_lds: wave-uniform LDS base + lane*16)
    const int e00 = tid >> 5, cs0 = tid & 31;
    const int nat_g0 = e00 * DIM + (cs0 ^ (e00 & 7)) * 8;            // + e0*DIM + i*2048
    const int d00 = tid >> 2, c00 = tid & 3;
    const int tr_g0  = d00 * TE + (c00 ^ ((d00 >> 1) & 3)) * 8;      // + e0 + i*64*TE
    const int l0     = wave * 1024;                                   // + i*4096

    // pre-loop: stage NAT(0)->buf0, NAT(1)->buf1, TR(0)->buf0
    #pragma unroll
    for (int i = 0; i < 4; i++)
        __builtin_amdgcn_global_load_lds(AS1(enc_b + (size_t)e_base * DIM + nat_g0 + i * 2048),
                                         AS3(lds + LDS_NAT0 + l0 + i * 4096), 16, 0, 0);
    #pragma unroll
    for (int i = 0; i < 4; i++)
        __builtin_amdgcn_global_load_lds(AS1(enc_b + (size_t)(e_base + 32) * DIM + nat_g0 + i * 2048),
                                         AS3(lds + LDS_NAT1 + l0 + i * 4096), 16, 0, 0);
    #pragma unroll
    for (int i = 0; i < 4; i++)
        __builtin_amdgcn_global_load_lds(AS1(enct_b + e_base + tr_g0 + i * 64 * TE),
                                         AS3(lds + LDS_TR0 + l0 + i * 4096), 16, 0, 0);

    // monolithic fallback: decoder passthrough
    if (nsplit == 1) {
        const float* dp = dec32 + ((size_t)b * TD + t0) * DIM;
        float*       op = out   + ((size_t)b * TD + t0) * 512;
        #pragma unroll
        for (int i = 0; i < 16; i++) {
            int idx = i * 256 + tid;
            int t = idx >> 6, c = idx & 63;
            float4 v = *(const float4*)(dp + t * DIM + c * 4);
            *(float4*)(op + t * 512 + c * 4) = v;
        }
    }

    // Q fragments (heavy only): B-operand B[k=q*8+j][n=tcol]
    f16x8 qf[2][8];
    if (heavy) {
        const float* qp = dec32 + ((size_t)b * TD + t0 + th * 32) * DIM;
        #pragma unroll
        for (int tn = 0; tn < 2; tn++)
            #pragma unroll
            for (int ks = 0; ks < 8; ks++) {
                const float* p = qp + (size_t)(tn * 16 + tcol) * DIM + ks * 32 + q * 8;
                float4 u = *(const float4*)(p);
                float4 v = *(const float4*)(p + 4);
                f16x8 o;
                o[0]=(f16)u.x; o[1]=(f16)u.y; o[2]=(f16)u.z; o[3]=(f16)u.w;
                o[4]=(f16)v.x; o[5]=(f16)v.y; o[6]=(f16)v.z; o[7]=(f16)v.w;
                qf[tn][ks] = o;
            }
    }

    f16x8 ones;
    #pragma unroll
    for (int j = 0; j < 8; j++) ones[j] = (f16)1.0f;

    const f32x4 zero4 = {0.f, 0.f, 0.f, 0.f};
    float m_[2] = {-INFINITY, -INFINITY};
    f32x4 lsum[2] = {zero4, zero4};
    f32x4 ctx[8][2];
    #pragma unroll
    for (int dm = 0; dm < 8; dm++)
        #pragma unroll
        for (int tn = 0; tn < 2; tn++) ctx[dm][tn] = zero4;

    const int e7 = tcol & 7;

    __syncthreads();   // NAT(0), NAT(1), TR(0) staged & visible

    for (int it = 0; it < iters; it++) {
        const int natc = (it & 1) ? LDS_NAT1 : LDS_NAT0;
        const int trc  = (it & 1) ? LDS_TR1  : LDS_TR0;
        char* pb = lds + LDS_P + ((it & 1) ? 5120 : 0) + th * 2560;

        if (heavy) {
            // ---- QK: St[e 32][t 32-slice] ----
            f32x4 st[2][2];
            #pragma unroll
            for (int mt = 0; mt < 2; mt++)
                #pragma unroll
                for (int tn = 0; tn < 2; tn++) st[mt][tn] = zero4;
            #pragma unroll
            for (int ks = 0; ks < 8; ks++) {
                #pragma unroll
                for (int mt = 0; mt < 2; mt++) {
                    int e = mt * 16 + tcol;
                    f16x8 af = *(const f16x8*)(lds + natc + e * 512 + (((ks << 2) | q) ^ e7) * 16);
                    #pragma unroll
                    for (int tn = 0; tn < 2; tn++)
                        st[mt][tn] = __builtin_amdgcn_mfma_f32_16x16x32_f16(af, qf[tn][ks], st[mt][tn], 0, 0, 0);
                }
            }
            // ---- online softmax + publish P, alpha ----
            #pragma unroll
            for (int tn = 0; tn < 2; tn++) {
                float mx = fmaxf(fmaxf(fmaxf(st[0][tn][0], st[0][tn][1]), fmaxf(st[0][tn][2], st[0][tn][3])),
                                 fmaxf(fmaxf(st[1][tn][0], st[1][tn][1]), fmaxf(st[1][tn][2], st[1][tn][3])));
                mx = fmaxf(mx, __shfl_xor(mx, 16, 64));
                mx = fmaxf(mx, __shfl_xor(mx, 32, 64));
                float mn = fmaxf(m_[tn], mx);
                bool bumped = mn > m_[tn];
                float al = __builtin_amdgcn_exp2f((m_[tn] - mn) * LOG2E);
                m_[tn] = mn;
                char* prow = pb + (tn * 16 + tcol) * 80;
                #pragma unroll
                for (int mt = 0; mt < 2; mt++) {
                    f16x4 pv;
                    #pragma unroll
                    for (int r = 0; r < 4; r++)
                        pv[r] = (f16)__builtin_amdgcn_exp2f((st[mt][tn][r] - mn) * LOG2E);
                    *(f16x4*)(prow + mt * 32 + q * 8) = pv;   // e = mt*16+q*4..+4
                }
                if (q == 0) *(float*)(prow + 72) = al;
                if (__any(bumped)) {
                    lsum[tn][0] *= al; lsum[tn][1] *= al; lsum[tn][2] *= al; lsum[tn][3] *= al;
                    #pragma unroll
                    for (int dm = 0; dm < 8; dm++) {
                        ctx[dm][tn][0] *= al; ctx[dm][tn][1] *= al;
                        ctx[dm][tn][2] *= al; ctx[dm][tn][3] *= al;
                    }
                }
            }
        }

        __syncthreads();   // ONLY barrier: P/alpha visible; drains prev-window staging (~free)

        // post-mid staging: TR(it+1) -> alt buffer; NAT(it+2) -> current-index buffer
        // (QK(it) readers of that buffer finished pre-mid). Full-window coverage.
        if (it + 1 < iters) {
            const int trn = (it & 1) ? LDS_TR0 : LDS_TR1;
            const int e1  = e_base + (it + 1) * 32;
            #pragma unroll
            for (int i = 0; i < 4; i++)
                __builtin_amdgcn_global_load_lds(AS1(enct_b + e1 + tr_g0 + i * 64 * TE),
                                                 AS3(lds + trn + l0 + i * 4096), 16, 0, 0);
        }
        if (it + 2 < iters) {
            const int e2 = e_base + (it + 2) * 32;
            #pragma unroll
            for (int i = 0; i < 4; i++)
                __builtin_amdgcn_global_load_lds(AS1(enc_b + (size_t)e2 * DIM + nat_g0 + i * 2048),
                                                 AS3(lds + natc + l0 + i * 4096), 16, 0, 0);
        }

        // light wave: adopt alpha, rescale accumulators
        if (!heavy) {
            #pragma unroll
            for (int tn = 0; tn < 2; tn++) {
                float al = *(const float*)(pb + (tn * 16 + tcol) * 80 + 72);
                if (__any(al < 1.0f)) {
                    lsum[tn][0] *= al; lsum[tn][1] *= al; lsum[tn][2] *= al; lsum[tn][3] *= al;
                    #pragma unroll
                    for (int dm = 0; dm < 8; dm++) {
                        ctx[dm][tn][0] *= al; ctx[dm][tn][1] *= al;
                        ctx[dm][tn][2] *= al; ctx[dm][tn][3] *= al;
                    }
                }
            }
        }

        // ---- PV: ctxT[d][t] += enc_t * P ; l via ones row ----
        f16x8 pf[2];
        #pragma unroll
        for (int tn = 0; tn < 2; tn++)
            pf[tn] = *(const f16x8*)(pb + (tn * 16 + tcol) * 80 + q * 16);
        #pragma unroll
        for (int tn = 0; tn < 2; tn++)
            lsum[tn] = __builtin_amdgcn_mfma_f32_16x16x32_f16(ones, pf[tn], lsum[tn], 0, 0, 0);
        #pragma unroll
        for (int dm = 0; dm < 8; dm++) {
            int drow = dh * 128 + dm * 16 + tcol;
            f16x8 af = *(const f16x8*)(lds + trc + drow * 64 + (q ^ ((tcol >> 1) & 3)) * 16);
            #pragma unroll
            for (int tn = 0; tn < 2; tn++)
                ctx[dm][tn] = __builtin_amdgcn_mfma_f32_16x16x32_f16(af, pf[tn], ctx[dm][tn], 0, 0, 0);
        }
        // no end barrier: P dbuf protects next-iter writes; NAT/TR targets proven race-free
    }

    // ---- epilogue ----
    if (nsplit > 1) {
        size_t rowbase = (size_t)(z * NB + b) * TD + t0 + th * 32;
        #pragma unroll
        for (int tn = 0; tn < 2; tn++) {
            float inv = 1.0f / lsum[tn][0];
            size_t rb = (rowbase + tn * 16 + tcol) * DIM + dh * 128;
            #pragma unroll
            for (int dm = 0; dm < 8; dm++) {
                f16x4 cv;
                #pragma unroll
                for (int r = 0; r < 4; r++) cv[r] = (f16)(ctx[dm][tn][r] * inv);
                *(f16x4*)(ctxp + rb + dm * 16 + q * 4) = cv;
            }
        }
        if (heavy && lane < 16) {
            int mi = (z * NB + b) * TD + t0 + th * 32 + lane;
            #pragma unroll
            for (int tn = 0; tn < 2; tn++) {
                m_arr[mi + tn * 16] = m_[tn];
                l_arr[mi + tn * 16] = lsum[tn][0];
            }
        }
    } else {
        float* ob = out + ((size_t)b * TD + t0 + th * 32) * 512 + 256 + dh * 128;
        #pragma unroll
        for (int tn = 0; tn < 2; tn++) {
            float inv = 1.0f / lsum[tn][0];
            #pragma unroll
            for (int dm = 0; dm < 8; dm++)
                #pragma unroll
                for (int r = 0; r < 4; r++)
                    ob[(size_t)(tn * 16 + tcol) * 512 + dm * 16 + q * 4 + r] = ctx[dm][tn][r] * inv;
        }
    }
}

// ---------------- combine: merge NSPLIT normalized partials + decoder passthrough ----------------
__global__ __launch_bounds__(256) void combine_kernel(const float* __restrict__ dec32,
        const f16* __restrict__ ctxp, const float* __restrict__ m_arr,
        const float* __restrict__ l_arr, float* __restrict__ out) {
    int idx  = blockIdx.x * 256 + threadIdx.x;
    int trow = idx >> 5;              // b*TD + t
    int dg   = (idx & 31) * 8;
    float m0[NSPLIT], l0[NSPLIT], M = -INFINITY;
    #pragma unroll
    for (int s = 0; s < NSPLIT; s++) {
        m0[s] = m_arr[s * (NB * TD) + trow];
        l0[s] = l_arr[s * (NB * TD) + trow];
        M = fmaxf(M, m0[s]);
    }
    float L = 0.f, w[NSPLIT];
    #pragma unroll
    for (int s = 0; s < NSPLIT; s++) {
        w[s] = __builtin_amdgcn_exp2f((m0[s] - M) * LOG2E) * l0[s];
        L += w[s];
    }
    float invL = 1.0f / L;
    float acc[8] = {0.f,0.f,0.f,0.f,0.f,0.f,0.f,0.f};
    #pragma unroll
    for (int s = 0; s < NSPLIT; s++) {
        f16x8 v = *(const f16x8*)(ctxp + ((size_t)s * (NB * TD) + trow) * DIM + dg);
        float ws = w[s] * invL;
        #pragma unroll
        for (int j = 0; j < 8; j++) acc[j] += ws * (float)v[j];
    }
    float4 d0 = *(const float4*)(dec32 + (size_t)trow * DIM + dg);
    float4 d1 = *(const float4*)(dec32 + (size_t)trow * DIM + dg + 4);
    float* ob = out + (size_t)trow * 512;
    *(float4*)(ob + dg)     = d0;
    *(float4*)(ob + dg + 4) = d1;
    float4 c0, c1;
    c0.x=acc[0]; c0.y=acc[1]; c0.z=acc[2]; c0.w=acc[3];
    c1.x=acc[4]; c1.y=acc[5]; c1.z=acc[6]; c1.w=acc[7];
    *(float4*)(ob + 256 + dg)     = c0;
    *(float4*)(ob + 256 + dg + 4) = c1;
}

extern "C" void kernel_launch(void* const* d_in, const int* in_sizes, int n_in,
                              void* d_out, int out_size, void* d_ws, size_t ws_size,
                              hipStream_t stream) {
    (void)in_sizes; (void)n_in;
    const float* enc = (const float*)d_in[0];
    const float* dec = (const float*)d_in[1];
    float* out = (float*)d_out;

    const size_t HB    = (size_t)NB * TE * DIM * 2;            // 8,388,608
    const size_t CTXPB = (size_t)NSPLIT * NB * TD * DIM * 2;   // 16,777,216
    const size_t MLB   = (size_t)NSPLIT * NB * TD * 4;         // 131,072
    const size_t NEED2 = 2 * HB + CTXPB + 2 * MLB;             // ~33.8 MB
    const size_t NEED1 = 2 * HB;

    if (ws_size < NEED1) {
        hipMemsetAsync(d_out, 0, (size_t)out_size * sizeof(float), stream);
        return;
    }
    int nsplit = (ws_size >= NEED2) ? NSPLIT : 1;

    f16*   enc_h = (f16*)d_ws;
    f16*   enc_t = (f16*)((char*)d_ws + HB);
    f16*   ctxp  = (f16*)((char*)d_ws + 2 * HB);
    float* m_arr = (float*)((char*)d_ws + 2 * HB + CTXPB);
    float* l_arr = (float*)((char*)d_ws + 2 * HB + CTXPB + MLB);

    prep_kernel<<<dim3(32, 4, 8), 256, 0, stream>>>(enc, enc_h, enc_t);
    attn_kernel<<<dim3(32, 8, nsplit), 256, 0, stream>>>(dec, enc_h, enc_t, out,
                                                         ctxp, m_arr, l_arr, nsplit);
    if (nsplit == NSPLIT)
        combine_kernel<<<2048, 256, 0, stream>>>(dec, ctxp, m_arr, l_arr, out);
}